// Round 1
// baseline (722.946 us; speedup 1.0000x reference)
//
#include <hip/hip_runtime.h>
#include <math.h>

// Problem constants (also derived at runtime from in_sizes)
// N=50000, E=1600000, F_IN=128, C_OUT=64, HEADS=2, HC=128

#define NEG_SLOPE 0.2f
#define GN_EPS 1e-5f

// ---------------------------------------------------------------------------
// K1: xl = x @ W_l, xr = x @ W_r   (x: n x 128, W: 128 x 128 each)
// Block: 256 threads, tile = 32 rows x 256 cols (col<128 -> W_l, else W_r).
// x tile staged in LDS; each thread owns 1 col x 32 rows.
// ---------------------------------------------------------------------------
__global__ __launch_bounds__(256) void gemm_xw(
    const float* __restrict__ x, const float* __restrict__ Wl,
    const float* __restrict__ Wr, float* __restrict__ xl,
    float* __restrict__ xr, int n) {
  __shared__ float xs[32][128];
  const int tid = threadIdx.x;
  const int r0 = blockIdx.x * 32;
  const int rows = min(32, n - r0);

  // stage x tile: 32*128 floats = 1024 float4, 4 per thread, coalesced
#pragma unroll
  for (int j = 0; j < 4; ++j) {
    int f4 = j * 256 + tid;     // 0..1023
    int row = f4 >> 5;          // 32 float4 per row
    int c4 = f4 & 31;
    float4 v = make_float4(0.f, 0.f, 0.f, 0.f);
    if (row < rows) v = ((const float4*)(x + (size_t)(r0 + row) * 128))[c4];
    ((float4*)&xs[row][0])[c4] = v;
  }
  __syncthreads();

  const int col = tid;
  const float* __restrict__ W = (col < 128) ? Wl : Wr;
  const int c = col & 127;

  float acc[32];
#pragma unroll
  for (int r = 0; r < 32; ++r) acc[r] = 0.f;

#pragma unroll 4
  for (int k = 0; k < 128; ++k) {
    float w = W[k * 128 + c];
#pragma unroll
    for (int r = 0; r < 32; ++r) acc[r] = fmaf(xs[r][k], w, acc[r]);
  }

  float* __restrict__ dst = (col < 128) ? xl : xr;
  for (int r = 0; r < rows; ++r) dst[(size_t)(r0 + r) * 128 + c] = acc[r];
}

// ---------------------------------------------------------------------------
// K2: histogram of dst (in-degree, excluding self loops)
// edge_index layout (2,E) row-major: src = ei[0..e), dst = ei[e..2e)
// ---------------------------------------------------------------------------
__global__ void hist_kernel(const int* __restrict__ ei, int* __restrict__ count,
                            int e) {
  int i = blockIdx.x * blockDim.x + threadIdx.x;
  if (i < e) atomicAdd(&count[ei[e + i]], 1);
}

// K3a: per-chunk (256 counts) sums
__global__ __launch_bounds__(256) void scan_chunks(const int* __restrict__ count,
                                                   int* __restrict__ chunkSum,
                                                   int n) {
  __shared__ int sd[256];
  int i = blockIdx.x * 256 + threadIdx.x;
  sd[threadIdx.x] = (i < n) ? count[i] : 0;
  __syncthreads();
#pragma unroll
  for (int s = 128; s > 0; s >>= 1) {
    if (threadIdx.x < s) sd[threadIdx.x] += sd[threadIdx.x + s];
    __syncthreads();
  }
  if (threadIdx.x == 0) chunkSum[blockIdx.x] = sd[0];
}

// K3b: serial exclusive scan of chunk sums (nchunk ~ 196, trivial)
__global__ void scan_top(const int* __restrict__ chunkSum,
                         int* __restrict__ chunkOff, int nchunk) {
  if (threadIdx.x == 0 && blockIdx.x == 0) {
    int run = 0;
    for (int i = 0; i < nchunk; ++i) {
      chunkOff[i] = run;
      run += chunkSum[i];
    }
  }
}

// K3c: per-chunk serial exclusive scan -> offsets + cursor
__global__ void scan_fill(const int* __restrict__ count,
                          const int* __restrict__ chunkOff,
                          int* __restrict__ offsets, int* __restrict__ cursor,
                          int n, int e) {
  if (threadIdx.x == 0) {
    int b = blockIdx.x;
    int run = chunkOff[b];
    for (int j = 0; j < 256; ++j) {
      int i = b * 256 + j;
      if (i < n) {
        offsets[i] = run;
        cursor[i] = run;
        run += count[i];
      }
    }
    if (b == 0) offsets[n] = e;
  }
}

// K4: scatter edges into CSR order (order within a segment irrelevant)
__global__ void scatter_kernel(const int* __restrict__ ei,
                               int* __restrict__ cursor,
                               int* __restrict__ csr_src, int e) {
  int i = blockIdx.x * blockDim.x + threadIdx.x;
  if (i < e) {
    int dst = ei[e + i];
    int pos = atomicAdd(&cursor[dst], 1);
    csr_src[pos] = ei[i];
  }
}

// ---------------------------------------------------------------------------
// K5: per-node online-softmax attention + aggregation.
// One wave (64 lanes) per node. lane = channel c; head0 = c, head1 = 64+c.
// Self-loop handled as implicit extra edge (src = node).
// Writes pre-GraphNorm output (+bias) to out.
// ---------------------------------------------------------------------------
__global__ __launch_bounds__(256) void node_agg(
    const float* __restrict__ xl, const float* __restrict__ xr,
    const int* __restrict__ offsets, const int* __restrict__ csr_src,
    const float* __restrict__ att, const float* __restrict__ bias,
    float* __restrict__ out, int n) {
  const int wave = threadIdx.x >> 6;
  const int lane = threadIdx.x & 63;
  const int node = blockIdx.x * 4 + wave;
  if (node >= n) return;

  const float xr0 = xr[(size_t)node * 128 + lane];
  const float xr1 = xr[(size_t)node * 128 + 64 + lane];
  const float a0 = att[lane];
  const float a1 = att[64 + lane];

  const int start = offsets[node];
  const int end = offsets[node + 1];

  float m0 = -INFINITY, m1 = -INFINITY;
  float s0 = 0.f, s1 = 0.f;
  float acc0 = 0.f, acc1 = 0.f;

  for (int e = start - 1; e < end; ++e) {
    const int src = (e < start) ? node : csr_src[e];  // wave-uniform
    const float* __restrict__ xls = xl + (size_t)src * 128;
    const float v0 = xls[lane];
    const float v1 = xls[64 + lane];

    float t0 = v0 + xr0;
    float t1 = v1 + xr1;
    t0 = (t0 > 0.f) ? t0 : NEG_SLOPE * t0;
    t1 = (t1 > 0.f) ? t1 : NEG_SLOPE * t1;
    float p0 = t0 * a0;
    float p1 = t1 * a1;
    // butterfly reduce over 64 lanes; all lanes end with the full sum
#pragma unroll
    for (int msk = 1; msk < 64; msk <<= 1) {
      p0 += __shfl_xor(p0, msk, 64);
      p1 += __shfl_xor(p1, msk, 64);
    }

    // online softmax update (p0/p1 are wave-uniform logits)
    float mn0 = fmaxf(m0, p0);
    float sc0 = __expf(m0 - mn0);  // 0 on first edge (m0 = -inf)
    float w0 = __expf(p0 - mn0);
    s0 = s0 * sc0 + w0;
    acc0 = fmaf(w0, v0, acc0 * sc0);
    m0 = mn0;

    float mn1 = fmaxf(m1, p1);
    float sc1 = __expf(m1 - mn1);
    float w1 = __expf(p1 - mn1);
    s1 = s1 * sc1 + w1;
    acc1 = fmaf(w1, v1, acc1 * sc1);
    m1 = mn1;
  }

  out[(size_t)node * 128 + lane] = acc0 / s0 + bias[lane];
  out[(size_t)node * 128 + 64 + lane] = acc1 / s1 + bias[64 + lane];
}

// ---------------------------------------------------------------------------
// K6a: per-channel sum & sumsq partials. Grid of G blocks x 256 threads.
// stride = G*256 is a multiple of 128, so each thread's channel is fixed.
// ---------------------------------------------------------------------------
__global__ __launch_bounds__(256) void gn_partial(const float* __restrict__ out,
                                                  float* __restrict__ part,
                                                  int total) {
  float s = 0.f, q = 0.f;
  const int stride = gridDim.x * 256;
  for (int idx = blockIdx.x * 256 + threadIdx.x; idx < total; idx += stride) {
    float v = out[idx];
    s += v;
    q = fmaf(v, v, q);
  }
  __shared__ float sd[256], qd[256];
  sd[threadIdx.x] = s;
  qd[threadIdx.x] = q;
  __syncthreads();
  if (threadIdx.x < 128) {
    part[blockIdx.x * 256 + threadIdx.x] = sd[threadIdx.x] + sd[threadIdx.x + 128];
    part[blockIdx.x * 256 + 128 + threadIdx.x] =
        qd[threadIdx.x] + qd[threadIdx.x + 128];
  }
}

// K6b: combine partials deterministically, produce affine params A,B
__global__ void gn_final(const float* __restrict__ part,
                         const float* __restrict__ gw,
                         const float* __restrict__ gb,
                         const float* __restrict__ gms, float* __restrict__ AB,
                         int nblocks, float inv_n) {
  int c = threadIdx.x;  // 128 threads
  float S = 0.f, Q = 0.f;
  for (int b = 0; b < nblocks; ++b) {
    S += part[b * 256 + c];
    Q += part[b * 256 + 128 + c];
  }
  float mean = S * inv_n;
  float msc = mean * gms[c];
  float var = Q * inv_n - 2.f * msc * mean + msc * msc;
  float scale = gw[c] * rsqrtf(var + GN_EPS);
  AB[c] = scale;
  AB[128 + c] = gb[c] - scale * msc;
}

// K7: in-place normalize, float4-vectorized
__global__ void gn_apply(float* __restrict__ out, const float* __restrict__ AB,
                         int total4) {
  int i = blockIdx.x * blockDim.x + threadIdx.x;
  if (i >= total4) return;
  float4 v = ((float4*)out)[i];
  int c4 = (i & 31) * 4;  // channel of .x
  v.x = fmaf(AB[c4 + 0], v.x, AB[128 + c4 + 0]);
  v.y = fmaf(AB[c4 + 1], v.y, AB[128 + c4 + 1]);
  v.z = fmaf(AB[c4 + 2], v.z, AB[128 + c4 + 2]);
  v.w = fmaf(AB[c4 + 3], v.w, AB[128 + c4 + 3]);
  ((float4*)out)[i] = v;
}

// ---------------------------------------------------------------------------
extern "C" void kernel_launch(void* const* d_in, const int* in_sizes, int n_in,
                              void* d_out, int out_size, void* d_ws,
                              size_t ws_size, hipStream_t stream) {
  const float* x = (const float*)d_in[0];
  const int* ei = (const int*)d_in[1];  // (2,E) int32
  const float* Wl = (const float*)d_in[2];
  const float* Wr = (const float*)d_in[3];
  const float* att = (const float*)d_in[4];
  const float* bias = (const float*)d_in[5];
  const float* gw = (const float*)d_in[6];
  const float* gb = (const float*)d_in[7];
  const float* gms = (const float*)d_in[8];
  float* out = (float*)d_out;

  const int n = in_sizes[0] / 128;  // 50000
  const int e = in_sizes[1] / 2;    // 1600000
  const int nchunk = (n + 255) / 256;
  const int GN_BLOCKS = 256;

  // workspace carve (256B aligned)
  char* w = (char*)d_ws;
  auto alloc = [&](size_t bytes) {
    char* p = w;
    w += (bytes + 255) & ~(size_t)255;
    return p;
  };
  float* xl = (float*)alloc((size_t)n * 128 * sizeof(float));
  float* xr = (float*)alloc((size_t)n * 128 * sizeof(float));
  int* count = (int*)alloc((size_t)n * sizeof(int));
  int* offsets = (int*)alloc((size_t)(n + 1) * sizeof(int));
  int* cursor = (int*)alloc((size_t)n * sizeof(int));
  int* csr_src = (int*)alloc((size_t)e * sizeof(int));
  int* chunkSum = (int*)alloc((size_t)nchunk * sizeof(int));
  int* chunkOff = (int*)alloc((size_t)nchunk * sizeof(int));
  float* part = (float*)alloc((size_t)GN_BLOCKS * 256 * sizeof(float));
  float* AB = (float*)alloc(256 * sizeof(float));

  hipMemsetAsync(count, 0, (size_t)n * sizeof(int), stream);

  gemm_xw<<<(n + 31) / 32, 256, 0, stream>>>(x, Wl, Wr, xl, xr, n);
  hist_kernel<<<(e + 255) / 256, 256, 0, stream>>>(ei, count, e);
  scan_chunks<<<nchunk, 256, 0, stream>>>(count, chunkSum, n);
  scan_top<<<1, 64, 0, stream>>>(chunkSum, chunkOff, nchunk);
  scan_fill<<<nchunk, 64, 0, stream>>>(count, chunkOff, offsets, cursor, n, e);
  scatter_kernel<<<(e + 255) / 256, 256, 0, stream>>>(ei, cursor, csr_src, e);
  node_agg<<<(n + 3) / 4, 256, 0, stream>>>(xl, xr, offsets, csr_src, att, bias,
                                            out, n);
  gn_partial<<<GN_BLOCKS, 256, 0, stream>>>(out, part, n * 128);
  gn_final<<<1, 128, 0, stream>>>(part, gw, gb, gms, AB, GN_BLOCKS,
                                  1.0f / (float)n);
  gn_apply<<<(n * 32 + 255) / 256, 256, 0, stream>>>(out, AB, n * 32);
}